// Round 4
// baseline (322.359 us; speedup 1.0000x reference)
//
#include <hip/hip_runtime.h>

// out[n,c,h,w] = sum_{c'} g[(c-c') mod 128] * act[n,c',h,w]
// where g = ifft(1 / fft(delta - k)), k = rolled zero-padded Ricker filter.
// C=128, S=H*W=4096 per image, 64 images.
//
// Rev 3b: resubmission of rev 3 (round-3 bench died to a container infra
// failure, not a kernel error; bounds re-audited). LDS-free, barrier-free
// streaming GEMM:
//   - Rev 2 fixed bank conflicts (1.68e7 -> 1e6) with ZERO speedup ->
//     bottleneck is phase serialization (load -> drain -> cvt -> LDS ->
//     barrier -> MFMA -> store), each CU getting half fair-share HBM BW.
//   - A-frags (m=s, k=c') loaded straight from global: lane(m=lane15,
//     k=quad*8+j) reads X[k][s]; 4x64B fully-used segments per instr; every
//     element loaded exactly once (wave owns disjoint 16-wide s-chunk).
//   - B-frags: circulant G has only 8 UNIQUE fragments (16*nt-32*kk mod 128
//     has 8 values) -> 8 bf16x8 in registers, gathered once per wave.
//   - Each wave streams 4 consecutive s-chunks, software-pipelined: issue
//     loads(t+1) between cvt(t) and MFMA(t); compiler emits counted vmcnt.
//   - No __syncthreads, no LDS.

typedef short bf16x8 __attribute__((ext_vector_type(8)));
typedef float f32x4 __attribute__((ext_vector_type(4)));

#define MFMA16x16x32 __builtin_amdgcn_mfma_f32_16x16x32_bf16

__device__ __forceinline__ unsigned short f2bf_rne(float f) {
  union { float f; unsigned u; } v; v.f = f;
  unsigned u = v.u;
  u += 0x7fffu + ((u >> 16) & 1u);   // round-to-nearest-even
  return (unsigned short)(u >> 16);
}

// ---------------------------------------------------------------------------
// Setup: compute g[128] as bf16 from the 27-tap filter. One block, 128 thr.
// kf[j] = filt[t] at j=(115+t)&127 (pad_left=50, roll by 65).
// Fk[m] = 1 - sum_t kf*e^{-2pi i j m/128};  g[n] = (1/128) Re sum_m e^{+2pi i mn/128}/Fk[m]
// ---------------------------------------------------------------------------
__global__ void build_g(const float* __restrict__ filt,
                        unsigned short* __restrict__ gbf) {
  __shared__ float ct[128], st[128], fr[128], fi[128];
  const int t = threadIdx.x;  // 0..127
  const float ang = (float)t * 0.049087385212340526f;  // 2*pi/128
  float s, c;
  __sincosf(ang, &s, &c);
  ct[t] = c; st[t] = s;
  __syncthreads();

  float re = 1.f, im = 0.f;
  for (int tt = 0; tt < 27; ++tt) {
    const int j = (115 + tt) & 127;
    const int idx = (j * t) & 127;
    const float kv = filt[tt];
    re -= kv * ct[idx];   // e^{-i a} = cos a - i sin a
    im += kv * st[idx];
  }
  fr[t] = re; fi[t] = im;
  __syncthreads();

  float acc = 0.f;
  for (int m = 0; m < 128; ++m) {
    const int idx = (m * t) & 127;
    const float dr = fr[m], di = fi[m];
    acc += (ct[idx] * dr + st[idx] * di) / (dr * dr + di * di);
  }
  gbf[t] = f2bf_rne(acc * (1.0f / 128.0f));
}

// ---------------------------------------------------------------------------
// Main kernel. Grid 1024 blocks x 256 thr (4 waves). Block covers one image's
// 256-wide s-window; wave w owns 64 consecutive s = 4 tiles of 16.
// Per tile: D[m=s(16)][n=c_out(128)] = sum_{k=c'(128)} X^T[s][c'] G[c'][c_out]
//   A-frag: lane(m=lane15, k=quad*8+j) = X[k][s_chunk+lane15]  (global dword)
//   B-frag: U[(nt-2kk)&7], U[t][j] = g[(16t + lane15 - 8quad - j) & 127]
//   D: col=lane15 = c_out, row=quad*4+reg = s-within-16 -> f32x4 stores.
// ---------------------------------------------------------------------------
__global__ __launch_bounds__(256, 3) void conv_inhib(
    const float* __restrict__ X, const unsigned short* __restrict__ gtab,
    float* __restrict__ Y) {
  const int tid = threadIdx.x;
  const int l = tid & 63;        // lane in wave
  const int w = tid >> 6;        // wave id 0..3
  const int lane15 = l & 15;
  const int quad = l >> 4;

  const int bid = blockIdx.x;               // 0..1023
  const int nimg = bid >> 4;                // 0..63
  const int sw = ((bid & 15) << 8) + (w << 6);  // wave s-base (64 wide)
  const float* Xn = X + (size_t)nimg * (128 * 4096);
  float* Yn = Y + (size_t)nimg * (128 * 4096);

  // ---- Persistent B fragments: 8 unique circulant frags, once per wave ----
  bf16x8 U[8];
#pragma unroll
  for (int t = 0; t < 8; ++t) {
    const int base = (t << 4) + lane15 - (quad << 3);
#pragma unroll
    for (int j = 0; j < 8; ++j)
      U[t][j] = (short)gtab[(base - j) & 127];
  }

  // per-lane column base: + row*4096 + 16*t walks the tiles
  const float* colbase = Xn + sw + lane15;
  const int rowoff = (quad << 3);  // quad*8

  // ---- Prologue: issue tile-0 loads ----
  float raw[32];
#pragma unroll
  for (int kk = 0; kk < 4; ++kk)
#pragma unroll
    for (int j = 0; j < 8; ++j)
      raw[(kk << 3) + j] = colbase[(size_t)((kk << 5) + rowoff + j) * 4096];

#pragma unroll
  for (int t = 0; t < 4; ++t) {
    // convert arrived tile t -> A fragments (compiler emits counted vmcnt)
    bf16x8 af[4];
#pragma unroll
    for (int kk = 0; kk < 4; ++kk)
#pragma unroll
      for (int j = 0; j < 8; ++j)
        af[kk][j] = (short)f2bf_rne(raw[(kk << 3) + j]);

    // issue tile t+1 loads; they fly under MFMA + stores below
    if (t < 3) {
      const float* nb = colbase + ((t + 1) << 4);
#pragma unroll
      for (int kk = 0; kk < 4; ++kk)
#pragma unroll
        for (int j = 0; j < 8; ++j)
          raw[(kk << 3) + j] = nb[(size_t)((kk << 5) + rowoff + j) * 4096];
    }

    // ---- 32 MFMAs: acc[nt] over 4 k-blocks ----
    f32x4 acc[8];
#pragma unroll
    for (int nt = 0; nt < 8; ++nt) acc[nt] = (f32x4){0.f, 0.f, 0.f, 0.f};
#pragma unroll
    for (int nt = 0; nt < 8; ++nt)
#pragma unroll
      for (int kk = 0; kk < 4; ++kk)
        acc[nt] = MFMA16x16x32(af[kk], U[(nt - 2 * kk) & 7], acc[nt], 0, 0, 0);

    // ---- Epilogue: f32x4 per (lane, nt) at c_out=nt*16+lane15 ----
    const int scol = sw + (t << 4) + (quad << 2);
#pragma unroll
    for (int nt = 0; nt < 8; ++nt) {
      *(f32x4*)(Yn + (size_t)((nt << 4) + lane15) * 4096 + scol) = acc[nt];
    }
  }
}

extern "C" void kernel_launch(void* const* d_in, const int* in_sizes, int n_in,
                              void* d_out, int out_size, void* d_ws, size_t ws_size,
                              hipStream_t stream) {
  const float* act = (const float*)d_in[0];   // (64,128,64,64) fp32
  const float* filt = (const float*)d_in[1];  // 27 fp32
  float* out = (float*)d_out;                 // (64,128,64,64) fp32
  unsigned short* g = (unsigned short*)d_ws;  // 128 bf16 scratch

  build_g<<<1, 128, 0, stream>>>(filt, g);
  conv_inhib<<<1024, 256, 0, stream>>>(act, g, out);
}

// Round 5
// 249.305 us; speedup vs baseline: 1.2930x; 1.2930x over previous
//
#include <hip/hip_runtime.h>

// out[n,c,h,w] = sum_{c'} g[(c-c') mod 128] * act[n,c',h,w]
// where g = ifft(1 / fft(delta - k)), k = rolled zero-padded Ricker filter.
// C=128, S=H*W=4096 per image, 64 images.
//
// Rev 4: DRAM-row-locality rewrite. Every kernel so far (64-128B segments at
// 16KB stride) pinned HBM at ~2.4 TB/s regardless of structure -> theory:
// activate-rate-limited DRAM (1 line-hit per row activation). This kernel
// makes every global access a >=1KB sequential run:
//   - loads: one 1KB row segment per wave instruction (64 lanes x float4),
//     8 consecutive 128B lines per DRAM row activation;
//   - stores: lane's c_out row fixed; 16-deep f32x4 burst = 1KB run per row
//     (rev2 proved this burst shape has zero write amplification);
//   - LDS [s][c] bf16 via register 8x4 micro-transpose + two-level XOR
//     swizzle key(s)=(s&7)^((s>>3)&7), conflict-free on write AND read.
// Block = 512 thr (8 waves), tile = [128 c][256 s], 64KB LDS, 1 barrier.

typedef short bf16x8 __attribute__((ext_vector_type(8)));
typedef float f32x4 __attribute__((ext_vector_type(4)));

#define MFMA16x16x32 __builtin_amdgcn_mfma_f32_16x16x32_bf16

__device__ __forceinline__ unsigned short f2bf_rne(float f) {
  union { float f; unsigned u; } v; v.f = f;
  unsigned u = v.u;
  u += 0x7fffu + ((u >> 16) & 1u);   // round-to-nearest-even
  return (unsigned short)(u >> 16);
}

__device__ __forceinline__ int lds_key(int s) {
  return (s & 7) ^ ((s >> 3) & 7);
}

// ---------------------------------------------------------------------------
// Setup: compute g[128] as bf16 from the 27-tap filter. One block, 128 thr.
// kf[j] = filt[t] at j=(115+t)&127 (pad_left=50, roll by 65).
// Fk[m] = 1 - sum_t kf*e^{-2pi i j m/128};  g[n] = (1/128) Re sum_m e^{+2pi i mn/128}/Fk[m]
// ---------------------------------------------------------------------------
__global__ void build_g(const float* __restrict__ filt,
                        unsigned short* __restrict__ gbf) {
  __shared__ float ct[128], st[128], fr[128], fi[128];
  const int t = threadIdx.x;  // 0..127
  const float ang = (float)t * 0.049087385212340526f;  // 2*pi/128
  float s, c;
  __sincosf(ang, &s, &c);
  ct[t] = c; st[t] = s;
  __syncthreads();

  float re = 1.f, im = 0.f;
  for (int tt = 0; tt < 27; ++tt) {
    const int j = (115 + tt) & 127;
    const int idx = (j * t) & 127;
    const float kv = filt[tt];
    re -= kv * ct[idx];   // e^{-i a} = cos a - i sin a
    im += kv * st[idx];
  }
  fr[t] = re; fi[t] = im;
  __syncthreads();

  float acc = 0.f;
  for (int m = 0; m < 128; ++m) {
    const int idx = (m * t) & 127;
    const float dr = fr[m], di = fi[m];
    acc += (ct[idx] * dr + st[idx] * di) / (dr * dr + di * di);
  }
  gbf[t] = f2bf_rne(acc * (1.0f / 128.0f));
}

// ---------------------------------------------------------------------------
// Main kernel. Grid 1024 blocks x 512 thr (8 waves). Block = one image's
// 256-wide s-tile, all 128 channels.
//   Staging: wave w loads rows c = 16w..16w+15, one row per instruction
//     (64 lanes x f32x4 = 1KB contiguous). Thread t holds X[c][s0+4t..4t+3]
//     for 16 rows -> two 8x4 register transposes -> ds_write_b128 into
//     Xt[s][c] bf16 (pitch 128), octet position = (c>>3) ^ key(s).
//   GEMM: D[m=s][n=c_out] = sum_k X^T[s][k] G[k][c_out]. Wave w owns
//     c_out = 16w + lane15 (n-tile of 16). A-frag: lane(m=lane15,k=quad*8+j)
//     <- Xt[mt*16+lane15][kk*32+quad*8+j] (b128, swizzled). B-frag:
//     U[kk][j] = g[(c_out - kk*32 - quad*8 - j) & 127], 4 register frags.
//   Epilogue: D col=lane15 (c_out fixed per lane!), row=quad*4+r = s ->
//     16 f32x4 stores walking s in 64B steps = 1KB sequential run per c row.
// ---------------------------------------------------------------------------
__global__ __launch_bounds__(512, 4) void conv_inhib(
    const float* __restrict__ X, const unsigned short* __restrict__ gtab,
    float* __restrict__ Y) {
  __shared__ __align__(16) unsigned short Xt[256 * 128];  // 64 KB

  const int tid = threadIdx.x;   // 0..511
  const int t = tid & 63;        // lane in wave
  const int w = tid >> 6;        // wave id 0..7
  const int lane15 = t & 15;
  const int quad = t >> 4;

  const int bid = blockIdx.x;          // 0..1023
  const int nimg = bid >> 4;           // 0..63
  const int s0 = (bid & 15) << 8;      // s-tile origin (256 cols)
  const float* Xn = X + (size_t)nimg * (128 * 4096);
  float* Yn = Y + (size_t)nimg * (128 * 4096);

  // ---- Stage: 16 x 1KB row loads (rows c = 16w .. 16w+15) ----
  f32x4 v[16];
  {
    const float* base = Xn + (size_t)(w << 4) * 4096 + s0 + (t << 2);
#pragma unroll
    for (int i = 0; i < 16; ++i)
      v[i] = *(const f32x4*)(base + (size_t)i * 4096);
  }

  // ---- Persistent B fragments (overlap with load latency) ----
  // U[kk][j] = g[(c_out - (kk*32 + quad*8 + j)) & 127], c_out = 16w + lane15
  const int cout = (w << 4) + lane15;
  bf16x8 U[4];
#pragma unroll
  for (int kk = 0; kk < 4; ++kk) {
    const int kb = cout - (kk << 5) - (quad << 3);
#pragma unroll
    for (int j = 0; j < 8; ++j)
      U[kk][j] = (short)gtab[(kb - j) & 127];
  }

  // ---- Register 8x4 transpose -> swizzled ds_write_b128 ----
#pragma unroll
  for (int b = 0; b < 2; ++b) {
    const int oct = (w << 1) + b;      // c-octet index (c = oct*8 + i)
#pragma unroll
    for (int j = 0; j < 4; ++j) {
      const int s = (t << 2) + j;      // 0..255
      bf16x8 q;
#pragma unroll
      for (int i = 0; i < 8; ++i) q[i] = (short)f2bf_rne(v[(b << 3) + i][j]);
      *(bf16x8*)&Xt[(s << 7) + ((oct ^ lds_key(s)) << 3)] = q;
    }
  }
  __syncthreads();

  // ---- GEMM: acc[mt] for mt = 0..15 (s-subtiles), K=128 ----
  f32x4 acc[16];
#pragma unroll
  for (int mt = 0; mt < 16; ++mt) acc[mt] = (f32x4){0.f, 0.f, 0.f, 0.f};

#pragma unroll
  for (int mt = 0; mt < 16; ++mt) {
    const int srow = (mt << 4) + lane15;
    const int key = lds_key(srow);
    const int rb = srow << 7;
#pragma unroll
    for (int kk = 0; kk < 4; ++kk) {
      const int oct = (kk << 2) + quad;
      const bf16x8 a = *(const bf16x8*)&Xt[rb + ((oct ^ key) << 3)];
      acc[mt] = MFMA16x16x32(a, U[kk], acc[mt], 0, 0, 0);
    }
  }

  // ---- Epilogue: 16-deep f32x4 burst, 1KB sequential run per c_out row ----
  {
    float* Yc = Yn + (size_t)cout * 4096 + s0 + (quad << 2);
#pragma unroll
    for (int mt = 0; mt < 16; ++mt) {
      *(f32x4*)(Yc + (mt << 4)) = acc[mt];
    }
  }
}

extern "C" void kernel_launch(void* const* d_in, const int* in_sizes, int n_in,
                              void* d_out, int out_size, void* d_ws, size_t ws_size,
                              hipStream_t stream) {
  const float* act = (const float*)d_in[0];   // (64,128,64,64) fp32
  const float* filt = (const float*)d_in[1];  // 27 fp32
  float* out = (float*)d_out;                 // (64,128,64,64) fp32
  unsigned short* g = (unsigned short*)d_ws;  // 128 bf16 scratch

  build_g<<<1, 128, 0, stream>>>(filt, g);
  conv_inhib<<<1024, 512, 0, stream>>>(act, g, out);
}